// Round 1
// baseline (166.653 us; speedup 1.0000x reference)
//
#include <hip/hip_runtime.h>
#include <hip/hip_bf16.h>

#define N_ROWS 8192
#define DIMS 64
#define MARGIN 1.1f
#define EPS 1e-8f
#define TILE 128
#define NB (N_ROWS / TILE)   // 64

typedef __bf16 bf16x8 __attribute__((ext_vector_type(8)));
typedef float f32x4 __attribute__((ext_vector_type(4)));

// ---------------- Kernel 1: row-normalize, f32 -> bf16, zero accumulator ----
__global__ __launch_bounds__(256) void normalize_kernel(const float* __restrict__ x,
                                                        __bf16* __restrict__ xn,
                                                        float* __restrict__ acc) {
    if (blockIdx.x == 0 && threadIdx.x == 0) acc[0] = 0.f;
    int row  = blockIdx.x * 4 + (threadIdx.x >> 6);   // one wave per row
    int lane = threadIdx.x & 63;                      // D == 64 == wave size
    float v  = x[row * DIMS + lane];
    float sq = v * v;
    #pragma unroll
    for (int off = 32; off; off >>= 1) sq += __shfl_xor(sq, off);
    float s = 1.f / fmaxf(sqrtf(sq), EPS);
    xn[row * DIMS + lane] = (__bf16)(v * s);
}

// ---------------- Kernel 2: tiled Gram + hinge loss, triangular grid --------
__global__ __launch_bounds__(256) void gram_loss_kernel(const __bf16* __restrict__ xn,
                                                        const int* __restrict__ cm,
                                                        float* __restrict__ acc) {
    const int bi = blockIdx.y;
    const int bj = blockIdx.x;
    if (bj < bi) return;   // symmetry: loss(i,j) == loss(j,i) exactly

    // 128 rows x 64 bf16 = 128 B/row, 16 KB per tile
    __shared__ __align__(16) char ldsA[TILE * 128];
    __shared__ __align__(16) char ldsB[TILE * 128];
    __shared__ int cmA[TILE];
    __shared__ int cmB[TILE];

    const int t    = threadIdx.x;
    const int lane = t & 63;
    const int wid  = t >> 6;

    const char* gA = (const char*)(xn + (size_t)bi * TILE * DIMS);
    const char* gB = (const char*)(xn + (size_t)bj * TILE * DIMS);

    // Stage via global_load_lds width=16. LDS dest is linear (wave-uniform
    // base + lane*16); XOR-swizzle is applied on the GLOBAL source address
    // (rule 21 / m173) so that LDS[row*128 + (c ^ ((row&7)<<4))] = G[row*128+c].
    #pragma unroll
    for (int q = 0; q < 4; ++q) {
        int p   = q * 4096 + t * 16;      // linear LDS byte position
        int row = p >> 7;
        int src = p ^ ((row & 7) << 4);   // involution within the 128B row
        __builtin_amdgcn_global_load_lds(
            (const __attribute__((address_space(1))) void*)(gA + src),
            (__attribute__((address_space(3))) void*)(ldsA + p), 16, 0, 0);
        __builtin_amdgcn_global_load_lds(
            (const __attribute__((address_space(1))) void*)(gB + src),
            (__attribute__((address_space(3))) void*)(ldsB + p), 16, 0, 0);
    }
    if (t < TILE) cmA[t] = cm[bi * TILE + t];
    else          cmB[t - TILE] = cm[bj * TILE + (t - TILE)];

    __syncthreads();

    // 4 waves in 2x2; each wave owns a 64x64 output sub-tile (4x4 fragments)
    const int wr   = wid >> 1;
    const int wc   = wid & 1;
    const int frow = lane & 15;   // A-row / B-col within fragment
    const int quad = lane >> 4;   // k-quarter: k = quad*8 + e  (bytes: quad*16)

    f32x4 acc4[4][4];
    #pragma unroll
    for (int m = 0; m < 4; ++m)
        #pragma unroll
        for (int n = 0; n < 4; ++n)
            acc4[m][n] = (f32x4){0.f, 0.f, 0.f, 0.f};

    #pragma unroll
    for (int kk = 0; kk < 2; ++kk) {          // K = 64 = 2 x 32
        bf16x8 a[4], b[4];
        #pragma unroll
        for (int m = 0; m < 4; ++m) {
            int row = wr * 64 + m * 16 + frow;
            int off = row * 128 + ((quad * 16 + kk * 64) ^ ((row & 7) << 4));
            a[m] = *(const bf16x8*)(ldsA + off);
        }
        #pragma unroll
        for (int n = 0; n < 4; ++n) {
            int row = wc * 64 + n * 16 + frow;
            int off = row * 128 + ((quad * 16 + kk * 64) ^ ((row & 7) << 4));
            b[n] = *(const bf16x8*)(ldsB + off);
        }
        #pragma unroll
        for (int m = 0; m < 4; ++m)
            #pragma unroll
            for (int n = 0; n < 4; ++n)
                acc4[m][n] = __builtin_amdgcn_mfma_f32_16x16x32_bf16(a[m], b[n], acc4[m][n], 0, 0, 0);
    }

    // Epilogue: hinge loss per element, per-lane sum.
    // C/D layout (m89-verified): col = lane&15, row = (lane>>4)*4 + reg
    float lsum = 0.f;
    #pragma unroll
    for (int m = 0; m < 4; ++m) {
        int rbase = wr * 64 + m * 16 + quad * 4;
        #pragma unroll
        for (int n = 0; n < 4; ++n) {
            int col = wc * 64 + n * 16 + frow;
            int cj  = cmB[col];
            #pragma unroll
            for (int r = 0; r < 4; ++r) {
                float dist = 1.f - acc4[m][n][r];
                float v = (cmA[rbase + r] == cj) ? dist
                                                 : fmaxf(MARGIN - dist, 0.f);
                lsum += v;
            }
        }
    }
    if (bi != bj) lsum *= 2.f;                 // off-diagonal tiles count twice

    #pragma unroll
    for (int off = 32; off; off >>= 1) lsum += __shfl_xor(lsum, off);
    if (lane == 0) atomicAdd(acc, lsum);
}

// ---------------- Kernel 3: finalize --------------------------------------
__global__ void finalize_kernel(const float* __restrict__ acc,
                                float* __restrict__ out) {
    out[0] = acc[0] * (1.f / ((float)N_ROWS * (float)N_ROWS));
}

extern "C" void kernel_launch(void* const* d_in, const int* in_sizes, int n_in,
                              void* d_out, int out_size, void* d_ws, size_t ws_size,
                              hipStream_t stream) {
    const float* bottleneck = (const float*)d_in[0];
    const int*   class_map  = (const int*)d_in[1];
    float* out = (float*)d_out;

    float*  acc = (float*)d_ws;                      // 4 B accumulator
    __bf16* xn  = (__bf16*)((char*)d_ws + 1024);     // 1 MB normalized bf16

    normalize_kernel<<<N_ROWS / 4, 256, 0, stream>>>(bottleneck, xn, acc);

    dim3 grid(NB, NB);
    gram_loss_kernel<<<grid, 256, 0, stream>>>(xn, class_map, acc);

    finalize_kernel<<<1, 1, 0, stream>>>(acc, out);
}

// Round 2
// 76.424 us; speedup vs baseline: 2.1806x; 2.1806x over previous
//
#include <hip/hip_runtime.h>
#include <hip/hip_bf16.h>

#define N_ROWS 8192
#define DIMS 64
#define MARGIN 1.1f
#define EPS 1e-8f
#define TILE 128
#define NB (N_ROWS / TILE)          // 64 row-tiles
#define NPAIRS (NB * (NB + 1) / 2)  // 2080 upper-triangle tile pairs
#define CHUNK 4                     // pairs per block
#define NGBLK (NPAIRS / CHUNK)      // 520 blocks

typedef __bf16 bf16x8 __attribute__((ext_vector_type(8)));
typedef float f32x4 __attribute__((ext_vector_type(4)));

// ---------------- Kernel 1: row-normalize, f32 -> bf16 ----------------------
__global__ __launch_bounds__(256) void normalize_kernel(const float* __restrict__ x,
                                                        __bf16* __restrict__ xn) {
    const int wid  = threadIdx.x >> 6;
    const int lane = threadIdx.x & 63;
    const int wave = blockIdx.x * 4 + wid;        // 2048 waves, 4 rows each
    #pragma unroll
    for (int r = 0; r < 4; ++r) {
        int row  = wave * 4 + r;
        float v  = x[row * DIMS + lane];
        float sq = v * v;
        #pragma unroll
        for (int off = 32; off; off >>= 1) sq += __shfl_xor(sq, off);
        float s = 1.f / fmaxf(sqrtf(sq), EPS);
        xn[row * DIMS + lane] = (__bf16)(v * s);
    }
}

// ---------------- Gram + hinge loss ----------------------------------------
__device__ __forceinline__ void gload16(const char* g, char* l) {
    __builtin_amdgcn_global_load_lds(
        (const __attribute__((address_space(1))) void*)g,
        (__attribute__((address_space(3))) void*)l, 16, 0, 0);
}

// Stage one (A,B) tile pair: 8 global_load_lds x 16B per thread.
// LDS dest linear; XOR-swizzle applied on the GLOBAL source (rule 21 / m173)
// so LDS[row*128 + (c ^ ((row&7)<<4))] = G[row*128 + c].
__device__ __forceinline__ void stage_pair(const __bf16* xn, int bi, int bj,
                                           char* ldsA, char* ldsB) {
    const int t = threadIdx.x;
    const char* gA = (const char*)(xn + (size_t)bi * TILE * DIMS);
    const char* gB = (const char*)(xn + (size_t)bj * TILE * DIMS);
    #pragma unroll
    for (int q = 0; q < 4; ++q) {
        int p   = q * 4096 + t * 16;      // linear LDS byte position
        int row = p >> 7;
        int src = p ^ ((row & 7) << 4);   // involution within the 128B row
        gload16(gA + src, ldsA + p);
        gload16(gB + src, ldsB + p);
    }
}

__global__ __launch_bounds__(256) void gram_loss_kernel(const __bf16* __restrict__ xn,
                                                        const int* __restrict__ cm,
                                                        float* __restrict__ partials) {
    __shared__ __align__(16) char lds[2][2][TILE * 128];   // [buf][A/B], 64 KB
    __shared__ float red[4];

    const int t    = threadIdx.x;
    const int lane = t & 63;
    const int wid  = t >> 6;
    const int wr   = wid >> 1;     // 2x2 waves, each owns 64x64 output
    const int wc   = wid & 1;
    const int frow = lane & 15;
    const int quad = lane >> 4;

    // chunk start: flattened upper-triangle pair index -> (bi, bj)
    int p0 = blockIdx.x * CHUNK;
    int bi = 0, base = 0;
    while (base + (NB - bi) <= p0) { base += (NB - bi); ++bi; }
    int bj = bi + (p0 - base);

    stage_pair(xn, bi, bj, lds[0][0], lds[0][1]);   // prologue prefetch

    float lsum = 0.f;
    int cbi = bi, cbj = bj;

    #pragma unroll
    for (int k = 0; k < CHUNK; ++k) {
        int nbi = cbi, nbj = cbj;
        if (k + 1 < CHUNK) {
            ++nbj;
            if (nbj == NB) { ++nbi; nbj = nbi; }
            stage_pair(xn, nbi, nbj, lds[(k + 1) & 1][0], lds[(k + 1) & 1][1]);
            asm volatile("s_waitcnt vmcnt(8)" ::: "memory");  // pair k landed; k+1 in flight
        } else {
            asm volatile("s_waitcnt vmcnt(0)" ::: "memory");
        }
        __builtin_amdgcn_sched_barrier(0);
        __builtin_amdgcn_s_barrier();            // raw barrier: no vmcnt(0) drain
        __builtin_amdgcn_sched_barrier(0);

        const char* ldsA = lds[k & 1][0];
        const char* ldsB = lds[k & 1][1];

        // class labels straight from global (L1/L2-hot; broadcast per 16-lane grp)
        int4 ca[4];
        #pragma unroll
        for (int m = 0; m < 4; ++m)
            ca[m] = *(const int4*)(cm + cbi * TILE + wr * 64 + m * 16 + quad * 4);
        int cb[4];
        #pragma unroll
        for (int n = 0; n < 4; ++n)
            cb[n] = cm[cbj * TILE + wc * 64 + n * 16 + frow];

        f32x4 acc4[4][4];
        #pragma unroll
        for (int m = 0; m < 4; ++m)
            #pragma unroll
            for (int n = 0; n < 4; ++n)
                acc4[m][n] = (f32x4){0.f, 0.f, 0.f, 0.f};

        #pragma unroll
        for (int kk = 0; kk < 2; ++kk) {          // K = 64 = 2 x 32
            bf16x8 a[4], b[4];
            #pragma unroll
            for (int m = 0; m < 4; ++m) {
                int row = wr * 64 + m * 16 + frow;
                int off = row * 128 + ((quad * 16 + kk * 64) ^ ((row & 7) << 4));
                a[m] = *(const bf16x8*)(ldsA + off);
            }
            #pragma unroll
            for (int n = 0; n < 4; ++n) {
                int row = wc * 64 + n * 16 + frow;
                int off = row * 128 + ((quad * 16 + kk * 64) ^ ((row & 7) << 4));
                b[n] = *(const bf16x8*)(ldsB + off);
            }
            #pragma unroll
            for (int m = 0; m < 4; ++m)
                #pragma unroll
                for (int n = 0; n < 4; ++n)
                    acc4[m][n] = __builtin_amdgcn_mfma_f32_16x16x32_bf16(a[m], b[n], acc4[m][n], 0, 0, 0);
        }

        // Epilogue: hinge per element. C/D layout: col=lane&15, row=(lane>>4)*4+reg
        float psum = 0.f;
        #pragma unroll
        for (int m = 0; m < 4; ++m) {
            int car[4] = {ca[m].x, ca[m].y, ca[m].z, ca[m].w};
            #pragma unroll
            for (int n = 0; n < 4; ++n) {
                #pragma unroll
                for (int r = 0; r < 4; ++r) {
                    float dist = 1.f - acc4[m][n][r];
                    psum += (car[r] == cb[n]) ? dist : fmaxf(MARGIN - dist, 0.f);
                }
            }
        }
        lsum += (cbi != cbj) ? 2.f * psum : psum;   // off-diagonal counts twice

        __builtin_amdgcn_s_barrier();            // done reading buf before overwrite
        cbi = nbi; cbj = nbj;
    }

    // block reduce -> partials[block] (no atomics anywhere)
    #pragma unroll
    for (int off = 32; off; off >>= 1) lsum += __shfl_xor(lsum, off);
    if (lane == 0) red[wid] = lsum;
    __syncthreads();
    if (t == 0) partials[blockIdx.x] = red[0] + red[1] + red[2] + red[3];
}

// ---------------- Kernel 3: finalize ---------------------------------------
__global__ __launch_bounds__(256) void finalize_kernel(const float* __restrict__ partials,
                                                       float* __restrict__ out) {
    const int lane = threadIdx.x & 63;
    const int wid  = threadIdx.x >> 6;
    float s = 0.f;
    for (int i = threadIdx.x; i < NGBLK; i += 256) s += partials[i];
    #pragma unroll
    for (int off = 32; off; off >>= 1) s += __shfl_xor(s, off);
    __shared__ float red[4];
    if (lane == 0) red[wid] = s;
    __syncthreads();
    if (threadIdx.x == 0)
        out[0] = (red[0] + red[1] + red[2] + red[3]) *
                 (1.f / ((float)N_ROWS * (float)N_ROWS));
}

extern "C" void kernel_launch(void* const* d_in, const int* in_sizes, int n_in,
                              void* d_out, int out_size, void* d_ws, size_t ws_size,
                              hipStream_t stream) {
    const float* bottleneck = (const float*)d_in[0];
    const int*   class_map  = (const int*)d_in[1];
    float* out = (float*)d_out;

    float*  partials = (float*)d_ws;                   // 520 floats
    __bf16* xnw      = (__bf16*)((char*)d_ws + 4096);  // 1 MB normalized bf16

    normalize_kernel<<<512, 256, 0, stream>>>(bottleneck, xnw);
    gram_loss_kernel<<<NGBLK, 256, 0, stream>>>(xnw, class_map, partials);
    finalize_kernel<<<1, 256, 0, stream>>>(partials, out);
}

// Round 3
// 71.710 us; speedup vs baseline: 2.3240x; 1.0657x over previous
//
#include <hip/hip_runtime.h>
#include <hip/hip_bf16.h>

#define N_ROWS 8192
#define DIMS 64
#define MARGIN 1.1f
#define EPS 1e-8f
#define TILE 128
#define NB 64                 // 64 row-tiles of 128
#define NGBLK 544             // sum over bi of ceil((NB-bi)/4)

typedef __bf16 bf16x8 __attribute__((ext_vector_type(8)));
typedef float f32x4 __attribute__((ext_vector_type(4)));

// ---------------- Kernel 1: row-normalize, f32 -> bf16 ----------------------
// lane handles (row = t>>4, cols 4*(t&15)..+3): float4 load, 4-shfl reduce.
__global__ __launch_bounds__(256) void normalize_kernel(const float* __restrict__ x,
                                                        __bf16* __restrict__ xn) {
    const int t   = blockIdx.x * 256 + threadIdx.x;
    const int row = t >> 4;
    const int c0  = (t & 15) * 4;
    float4 v = *(const float4*)(x + row * DIMS + c0);
    float sq = v.x * v.x + v.y * v.y + v.z * v.z + v.w * v.w;
    sq += __shfl_xor(sq, 1);
    sq += __shfl_xor(sq, 2);
    sq += __shfl_xor(sq, 4);
    sq += __shfl_xor(sq, 8);
    float s = 1.f / fmaxf(sqrtf(sq), EPS);
    union { ushort4 u; __bf16 h[4]; } o;
    o.h[0] = (__bf16)(v.x * s);
    o.h[1] = (__bf16)(v.y * s);
    o.h[2] = (__bf16)(v.z * s);
    o.h[3] = (__bf16)(v.w * s);
    *(ushort4*)(xn + row * DIMS + c0) = o.u;
}

// ---------------- Gram + hinge loss ----------------------------------------
__device__ __forceinline__ void gload16(const char* g, char* l) {
    __builtin_amdgcn_global_load_lds(
        (const __attribute__((address_space(1))) void*)g,
        (__attribute__((address_space(3))) void*)l, 16, 0, 0);
}

// Stage one 128x64 bf16 tile (16 KB): 4 x global_load_lds(16B) per thread.
// LDS dest linear; XOR-swizzle on the GLOBAL source (rule 21 / m173) so
// LDS[row*128 + (c ^ ((row&7)<<4))] = G[row*128 + c].
__device__ __forceinline__ void stage_tile(const __bf16* xn, int bt, char* lds) {
    const int t = threadIdx.x;
    const char* g = (const char*)(xn + (size_t)bt * TILE * DIMS);
    #pragma unroll
    for (int q = 0; q < 4; ++q) {
        int p   = q * 4096 + t * 16;      // linear LDS byte position
        int row = p >> 7;
        int src = p ^ ((row & 7) << 4);   // involution within the 128B row
        gload16(g + src, lds + p);
    }
}

// Block = (bi, chunk of up to 4 bj >= bi). A staged once, B double-buffered.
__global__ __launch_bounds__(256, 3) void gram_loss_kernel(const __bf16* __restrict__ xn,
                                                           const int* __restrict__ cm,
                                                           float* __restrict__ partials) {
    __shared__ __align__(16) char ldsA[TILE * 128];       // 16 KB
    __shared__ __align__(16) char ldsB[2][TILE * 128];    // 32 KB
    __shared__ float red[4];

    const int t    = threadIdx.x;
    const int lane = t & 63;
    const int wid  = t >> 6;
    const int wr   = wid >> 1;     // 2x2 waves, each owns a 64x64 output
    const int wc   = wid & 1;
    const int frow = lane & 15;
    const int quad = lane >> 4;

    // block -> (bi, bj0): strips of bj chunked by 4
    int b = blockIdx.x, bi = 0, base = 0;
    for (;;) {
        int nc = (NB - bi + 3) >> 2;
        if (b < base + nc) break;
        base += nc; ++bi;
    }
    const int bj0   = bi + ((b - base) << 2);
    const int npair = min(4, NB - bj0);

    stage_tile(xn, bi, ldsA);          // prologue: A + first B
    stage_tile(xn, bj0, ldsB[0]);

    // A-side classes: once per block (16 per-lane row labels)
    int4 ca4[4];
    #pragma unroll
    for (int m = 0; m < 4; ++m)
        ca4[m] = *(const int4*)(cm + bi * TILE + wr * 64 + m * 16 + quad * 4);

    bf16x8 afrag[2][4];
    float lsum_diag = 0.f, lsum_off = 0.f;

    for (int k = 0; k < npair; ++k) {
        const int bj = bj0 + k;
        if (k + 1 < npair) {
            stage_tile(xn, bj + 1, ldsB[(k + 1) & 1]);
            asm volatile("s_waitcnt vmcnt(4)" ::: "memory");  // tile k landed; k+1 in flight
        } else {
            asm volatile("s_waitcnt vmcnt(0)" ::: "memory");
        }
        __builtin_amdgcn_sched_barrier(0);
        __builtin_amdgcn_s_barrier();          // raw barrier: no vmcnt(0) drain
        __builtin_amdgcn_sched_barrier(0);

        if (k == 0) {                           // A fragments: once per block
            #pragma unroll
            for (int kk = 0; kk < 2; ++kk)
                #pragma unroll
                for (int m = 0; m < 4; ++m) {
                    int row = wr * 64 + m * 16 + frow;
                    int off = row * 128 + ((quad * 16 + kk * 64) ^ ((row & 7) << 4));
                    afrag[kk][m] = *(const bf16x8*)(ldsA + off);
                }
        }

        int cb[4];                              // B-side classes for this pair
        #pragma unroll
        for (int n = 0; n < 4; ++n)
            cb[n] = cm[bj * TILE + wc * 64 + n * 16 + frow];

        const char* ldsBk = ldsB[k & 1];
        f32x4 acc4[4][4];
        #pragma unroll
        for (int m = 0; m < 4; ++m)
            #pragma unroll
            for (int n = 0; n < 4; ++n)
                acc4[m][n] = (f32x4){0.f, 0.f, 0.f, 0.f};

        #pragma unroll
        for (int kk = 0; kk < 2; ++kk) {        // K = 64 = 2 x 32
            bf16x8 bfr[4];
            #pragma unroll
            for (int n = 0; n < 4; ++n) {
                int row = wc * 64 + n * 16 + frow;
                int off = row * 128 + ((quad * 16 + kk * 64) ^ ((row & 7) << 4));
                bfr[n] = *(const bf16x8*)(ldsBk + off);
            }
            #pragma unroll
            for (int m = 0; m < 4; ++m)
                #pragma unroll
                for (int n = 0; n < 4; ++n)
                    acc4[m][n] = __builtin_amdgcn_mfma_f32_16x16x32_bf16(afrag[kk][m], bfr[n], acc4[m][n], 0, 0, 0);
        }

        // hinge epilogue; C/D layout: col = lane&15, row = (lane>>4)*4 + reg
        float psum = 0.f;
        #pragma unroll
        for (int m = 0; m < 4; ++m) {
            int car[4] = {ca4[m].x, ca4[m].y, ca4[m].z, ca4[m].w};
            #pragma unroll
            for (int n = 0; n < 4; ++n) {
                #pragma unroll
                for (int r = 0; r < 4; ++r) {
                    float c = acc4[m][n][r];
                    float d = 1.f - c;
                    float h = fmaxf(c + (MARGIN - 1.f), 0.f);
                    psum += (car[r] == cb[n]) ? d : h;
                }
            }
        }
        if (bi == bj) lsum_diag += psum; else lsum_off += psum;

        __builtin_amdgcn_s_barrier();           // done reading buf before overwrite
    }

    float lsum = lsum_diag + 2.f * lsum_off;    // off-diagonal tiles count twice
    #pragma unroll
    for (int off = 32; off; off >>= 1) lsum += __shfl_xor(lsum, off);
    if (lane == 0) red[wid] = lsum;
    __syncthreads();
    if (t == 0) partials[blockIdx.x] = red[0] + red[1] + red[2] + red[3];
}

// ---------------- Kernel 3: finalize ---------------------------------------
__global__ __launch_bounds__(256) void finalize_kernel(const float* __restrict__ partials,
                                                       float* __restrict__ out) {
    const int lane = threadIdx.x & 63;
    const int wid  = threadIdx.x >> 6;
    float s = 0.f;
    for (int i = threadIdx.x; i < NGBLK; i += 256) s += partials[i];
    #pragma unroll
    for (int off = 32; off; off >>= 1) s += __shfl_xor(s, off);
    __shared__ float red[4];
    if (lane == 0) red[wid] = s;
    __syncthreads();
    if (threadIdx.x == 0)
        out[0] = (red[0] + red[1] + red[2] + red[3]) *
                 (1.f / ((float)N_ROWS * (float)N_ROWS));
}

extern "C" void kernel_launch(void* const* d_in, const int* in_sizes, int n_in,
                              void* d_out, int out_size, void* d_ws, size_t ws_size,
                              hipStream_t stream) {
    const float* bottleneck = (const float*)d_in[0];
    const int*   class_map  = (const int*)d_in[1];
    float* out = (float*)d_out;

    float*  partials = (float*)d_ws;                   // 544 floats
    __bf16* xnw      = (__bf16*)((char*)d_ws + 4096);  // 1 MB normalized bf16

    normalize_kernel<<<512, 256, 0, stream>>>(bottleneck, xnw);
    gram_loss_kernel<<<NGBLK, 256, 0, stream>>>(xnw, class_map, partials);
    finalize_kernel<<<1, 256, 0, stream>>>(partials, out);
}

// Round 4
// 71.541 us; speedup vs baseline: 2.3295x; 1.0024x over previous
//
#include <hip/hip_runtime.h>
#include <hip/hip_bf16.h>

#define N_ROWS 8192
#define DIMS 64
#define MARGIN 1.1f
#define EPS 1e-8f
#define TILE 128
#define NB 64                       // 64 row-tiles of 128
#define NPAIRS (NB * (NB + 1) / 2)  // 2080 upper-triangle tile pairs

typedef __bf16 bf16x8 __attribute__((ext_vector_type(8)));
typedef float f32x4 __attribute__((ext_vector_type(4)));

// ---------------- Kernel 1: row-normalize, f32 -> bf16 ----------------------
// lane handles (row = t>>4, cols 4*(t&15)..+3): float4 load, 4-shfl reduce.
__global__ __launch_bounds__(256) void normalize_kernel(const float* __restrict__ x,
                                                        __bf16* __restrict__ xn) {
    const int t   = blockIdx.x * 256 + threadIdx.x;
    const int row = t >> 4;
    const int c0  = (t & 15) * 4;
    float4 v = *(const float4*)(x + row * DIMS + c0);
    float sq = v.x * v.x + v.y * v.y + v.z * v.z + v.w * v.w;
    sq += __shfl_xor(sq, 1);
    sq += __shfl_xor(sq, 2);
    sq += __shfl_xor(sq, 4);
    sq += __shfl_xor(sq, 8);
    float s = 1.f / fmaxf(sqrtf(sq), EPS);
    union { ushort4 u; __bf16 h[4]; } o;
    o.h[0] = (__bf16)(v.x * s);
    o.h[1] = (__bf16)(v.y * s);
    o.h[2] = (__bf16)(v.z * s);
    o.h[3] = (__bf16)(v.w * s);
    *(ushort4*)(xn + row * DIMS + c0) = o.u;
}

// ---------------- Gram + hinge loss ----------------------------------------
__device__ __forceinline__ void gload16(const char* g, char* l) {
    __builtin_amdgcn_global_load_lds(
        (const __attribute__((address_space(1))) void*)g,
        (__attribute__((address_space(3))) void*)l, 16, 0, 0);
}

// Stage one 128x64 bf16 tile (16 KB): 4 x global_load_lds(16B) per thread.
// LDS dest linear; XOR-swizzle on the GLOBAL source (rule 21 / m173) so
// LDS[row*128 + (c ^ ((row&7)<<4))] = G[row*128 + c].
__device__ __forceinline__ void stage_tile(const __bf16* xn, int bt, char* lds) {
    const int t = threadIdx.x;
    const char* g = (const char*)(xn + (size_t)bt * TILE * DIMS);
    #pragma unroll
    for (int q = 0; q < 4; ++q) {
        int p   = q * 4096 + t * 16;      // linear LDS byte position
        int row = p >> 7;
        int src = p ^ ((row & 7) << 4);   // involution within the 128B row
        gload16(g + src, lds + p);
    }
}

// One tile-pair per block: max block-level TLP, single barrier phase.
__global__ __launch_bounds__(256, 4) void gram_loss_kernel(const __bf16* __restrict__ xn,
                                                           const int* __restrict__ cm,
                                                           float* __restrict__ partials) {
    __shared__ __align__(16) char ldsA[TILE * 128];   // 16 KB
    __shared__ __align__(16) char ldsB[TILE * 128];   // 16 KB
    __shared__ float red[4];

    const int t    = threadIdx.x;
    const int lane = t & 63;
    const int wid  = t >> 6;
    const int wr   = wid >> 1;     // 2x2 waves, each owns a 64x64 output
    const int wc   = wid & 1;
    const int frow = lane & 15;
    const int quad = lane >> 4;

    // closed-form triangular decode: f(bi) = bi*(2*NB - bi + 1)/2 pairs before row bi
    const int p = blockIdx.x;
    int bi = (int)(((2.f * NB + 1.f) -
                    sqrtf((2.f * NB + 1.f) * (2.f * NB + 1.f) - 8.f * (float)p)) * 0.5f);
    while ((bi + 1) * (2 * NB - bi) / 2 <= p) ++bi;      // fixup (float rounding)
    while (bi * (2 * NB - bi + 1) / 2 > p) --bi;
    const int bj = bi + (p - bi * (2 * NB - bi + 1) / 2);

    // issue all staging ASAP; labels ride behind them in the VMEM queue
    stage_tile(xn, bi, ldsA);
    stage_tile(xn, bj, ldsB);

    int4 ca4[4];
    #pragma unroll
    for (int m = 0; m < 4; ++m)
        ca4[m] = *(const int4*)(cm + bi * TILE + wr * 64 + m * 16 + quad * 4);
    int cb[4];
    #pragma unroll
    for (int n = 0; n < 4; ++n)
        cb[n] = cm[bj * TILE + wc * 64 + n * 16 + frow];

    asm volatile("s_waitcnt vmcnt(0)" ::: "memory");
    __builtin_amdgcn_sched_barrier(0);
    __builtin_amdgcn_s_barrier();          // raw barrier (waves already drained)
    __builtin_amdgcn_sched_barrier(0);

    f32x4 acc4[4][4];
    #pragma unroll
    for (int m = 0; m < 4; ++m)
        #pragma unroll
        for (int n = 0; n < 4; ++n)
            acc4[m][n] = (f32x4){0.f, 0.f, 0.f, 0.f};

    #pragma unroll
    for (int kk = 0; kk < 2; ++kk) {        // K = 64 = 2 x 32
        bf16x8 a[4], b[4];
        #pragma unroll
        for (int m = 0; m < 4; ++m) {
            int row = wr * 64 + m * 16 + frow;
            int off = row * 128 + ((quad * 16 + kk * 64) ^ ((row & 7) << 4));
            a[m] = *(const bf16x8*)(ldsA + off);
        }
        #pragma unroll
        for (int n = 0; n < 4; ++n) {
            int row = wc * 64 + n * 16 + frow;
            int off = row * 128 + ((quad * 16 + kk * 64) ^ ((row & 7) << 4));
            b[n] = *(const bf16x8*)(ldsB + off);
        }
        #pragma unroll
        for (int m = 0; m < 4; ++m)
            #pragma unroll
            for (int n = 0; n < 4; ++n)
                acc4[m][n] = __builtin_amdgcn_mfma_f32_16x16x32_bf16(a[m], b[n], acc4[m][n], 0, 0, 0);
    }

    // hinge epilogue; C/D layout: col = lane&15, row = (lane>>4)*4 + reg
    float psum = 0.f;
    #pragma unroll
    for (int m = 0; m < 4; ++m) {
        int car[4] = {ca4[m].x, ca4[m].y, ca4[m].z, ca4[m].w};
        #pragma unroll
        for (int n = 0; n < 4; ++n) {
            #pragma unroll
            for (int r = 0; r < 4; ++r) {
                float c = acc4[m][n][r];
                float d = 1.f - c;
                float h = fmaxf(c + (MARGIN - 1.f), 0.f);
                psum += (car[r] == cb[n]) ? d : h;
            }
        }
    }
    float lsum = (bi != bj) ? 2.f * psum : psum;   // off-diagonal counts twice

    #pragma unroll
    for (int off = 32; off; off >>= 1) lsum += __shfl_xor(lsum, off);
    if (lane == 0) red[wid] = lsum;
    __syncthreads();
    if (t == 0) partials[blockIdx.x] = red[0] + red[1] + red[2] + red[3];
}

// ---------------- Kernel 3: finalize ---------------------------------------
__global__ __launch_bounds__(256) void finalize_kernel(const float* __restrict__ partials,
                                                       float* __restrict__ out) {
    const int lane = threadIdx.x & 63;
    const int wid  = threadIdx.x >> 6;
    float s = 0.f;
    for (int i = threadIdx.x; i < NPAIRS; i += 256) s += partials[i];
    #pragma unroll
    for (int off = 32; off; off >>= 1) s += __shfl_xor(s, off);
    __shared__ float red[4];
    if (lane == 0) red[wid] = s;
    __syncthreads();
    if (threadIdx.x == 0)
        out[0] = (red[0] + red[1] + red[2] + red[3]) *
                 (1.f / ((float)N_ROWS * (float)N_ROWS));
}

extern "C" void kernel_launch(void* const* d_in, const int* in_sizes, int n_in,
                              void* d_out, int out_size, void* d_ws, size_t ws_size,
                              hipStream_t stream) {
    const float* bottleneck = (const float*)d_in[0];
    const int*   class_map  = (const int*)d_in[1];
    float* out = (float*)d_out;

    float*  partials = (float*)d_ws;                    // 2080 floats
    __bf16* xnw      = (__bf16*)((char*)d_ws + 65536);  // 1 MB normalized bf16

    normalize_kernel<<<512, 256, 0, stream>>>(bottleneck, xnw);
    gram_loss_kernel<<<NPAIRS, 256, 0, stream>>>(xnw, class_map, partials);
    finalize_kernel<<<1, 256, 0, stream>>>(partials, out);
}